// Round 10
// baseline (218.563 us; speedup 1.0000x reference)
//
#include <hip/hip_runtime.h>
#include <hip/hip_bf16.h>

// GDGCN: out[b,c,m,t] = sum_n softmax_row(relu(t1 nv2^T))[n,m] * x[b,c,n,t]
// t1 = nv1 @ (sum_d tv[d] k[d,:,:]);  N=8192, D=32, cols = B*C*T = 192.
// R10: k_mega = PRODUCER/CONSUMER wave specialization. 4 producer waves
// generate E (32x32 logit MFMA -> exp2 -> C-layout b64 LDS writes) into a
// 3-slot ring; 4 consumer waves each own 32 m x 192 cols (24 acc MFMAs +
// 4 LDS b128 B-frags per 64-n stage). Sync = monotonic LDS counters +
// s_sleep spin (lane-0 atomics, threadfence_block). NO __syncthreads in
// the loop, no lockstep: the barrier-drain that capped R8 at 74 us is gone.

#define NN 8192
#define DD 32
#define TT 12
#define NSPLIT 8
#define CHUNK 1024
#define RSLOT 3

typedef __attribute__((ext_vector_type(8))) short bf16x8;
typedef __attribute__((ext_vector_type(4))) short bf16x4;
typedef __attribute__((ext_vector_type(4))) float f32x4;
typedef __attribute__((ext_vector_type(16))) float f32x16;

static __device__ __forceinline__ unsigned short f2bf(float f) {
  unsigned int u = __float_as_uint(f);
  u = (u + 0x7FFFu + ((u >> 16) & 1u)) >> 16;  // RNE bf16
  return (unsigned short)u;
}

static __device__ __forceinline__ float fexp2(float x) {
#if __has_builtin(__builtin_amdgcn_exp2f)
  return __builtin_amdgcn_exp2f(x);
#else
  return __builtin_exp2f(x);
#endif
}

// ---- fused: core = tv.k ; t1 = (nv1@core)*log2e (bf16) ; nv2 -> bf16 ; sums=0
__global__ __launch_bounds__(256) void k_prep(const float* __restrict__ nv1,
                                              const float* __restrict__ nv2,
                                              const float* __restrict__ timevec,
                                              const float* __restrict__ kk,
                                              const int* __restrict__ tind,
                                              unsigned short* __restrict__ t1b,
                                              unsigned short* __restrict__ nv2b,
                                              float* __restrict__ sums) {
  __shared__ float cs[1024];
  const int tid = threadIdx.x;
  if (tid < 128) sums[blockIdx.x * 128 + tid] = 0.f;
  const float* tv = timevec + (size_t)tind[0] * DD;
  for (int idx = tid; idx < 1024; idx += 256) {
    float acc = 0.f;
#pragma unroll
    for (int d = 0; d < DD; ++d) acc += tv[d] * kk[d * 1024 + idx];
    cs[idx] = acc;
  }
  __syncthreads();
  const int nbase = blockIdx.x * 128;
  const int f = tid & 31, sub = tid >> 5;
#pragma unroll 4
  for (int it = 0; it < 16; ++it) {
    const int n = nbase + it * 8 + sub;
    const float* nr = nv1 + (size_t)n * DD;
    float acc = 0.f;
#pragma unroll
    for (int e = 0; e < DD; ++e) acc += nr[e] * cs[e * DD + f];
    t1b[(size_t)n * DD + f] = f2bf(acc * 1.4426950408889634f);  // fold log2(e)
  }
#pragma unroll 4
  for (int it = 0; it < 16; ++it) {
    const int idx = nbase * DD + it * 256 + tid;
    nv2b[idx] = f2bf(nv2[idx]);
  }
}

// ---- sums[n] += sum_m exp2(relu(t1[n].nv2[m]))  grid (128 n, 8 m-chunks) ----
__global__ __launch_bounds__(256) void k_stats(const unsigned short* __restrict__ t1b,
                                               const unsigned short* __restrict__ nv2b,
                                               float* __restrict__ sums) {
  const int tid = threadIdx.x;
  const int w = tid >> 6, lane = tid & 63, q = lane >> 4, i16 = lane & 15;
  const int nbase = blockIdx.x * 64 + w * 16;
  bf16x8 a = *(const bf16x8*)(t1b + (size_t)(nbase + i16) * DD + q * 8);
  const f32x4 z4 = {0.f, 0.f, 0.f, 0.f};
  float s[4] = {0.f, 0.f, 0.f, 0.f};
  const int m0 = blockIdx.y * 1024;
  for (int mt = m0; mt < m0 + 1024; mt += 64) {
#pragma unroll
    for (int u = 0; u < 4; ++u) {
      bf16x8 b = *(const bf16x8*)(nv2b + (size_t)(mt + u * 16 + i16) * DD + q * 8);
      f32x4 d = __builtin_amdgcn_mfma_f32_16x16x32_bf16(a, b, z4, 0, 0, 0);
#pragma unroll
      for (int r = 0; r < 4; ++r) s[r] += fexp2(fmaxf(d[r], 0.f));
    }
  }
#pragma unroll
  for (int r = 0; r < 4; ++r)
    for (int off = 1; off < 16; off <<= 1) s[r] += __shfl_xor(s[r], off, 64);
  if (i16 == 0) {
#pragma unroll
    for (int r = 0; r < 4; ++r) atomicAdd(&sums[nbase + q * 4 + r], s[r]);
  }
}

// ---- yT[col][n] = bf16(x[bc][n][t] / sums[n]) via LDS transpose ----
__global__ __launch_bounds__(256) void k_y(const float* __restrict__ x,
                                           const float* __restrict__ sums,
                                           unsigned short* __restrict__ yT) {
  __shared__ float xs[3072];
  const int tid = threadIdx.x;
  const int n0 = blockIdx.x * 256;
  const int bc = blockIdx.y;
  const float* xp = x + (size_t)bc * NN * TT + (size_t)n0 * TT;
#pragma unroll
  for (int j = 0; j < 12; ++j) xs[j * 256 + tid] = xp[j * 256 + tid];
  __syncthreads();
  const float rinv = 1.0f / sums[n0 + tid];
#pragma unroll
  for (int t = 0; t < 12; ++t)
    yT[(size_t)(bc * TT + t) * NN + n0 + tid] = f2bf(xs[tid * 12 + t] * rinv);
}

// ---- k_mega: part[nc][col][m] = sum_{n in chunk} E[n][m] * y[col][n] ----
// grid (64 m-blocks of 128, 8 chunks of 1024 n); 512 thr = 8 waves.
// Waves 0-3 PRODUCE: wave p owns m rows [mb+p*32,+32); per 64-n stage:
//   4 gen MFMAs (32x32x16, chained K=32) -> 32 exp2 -> 8 swizzled b64 writes
//   into ring slot Et[s][m 0..127][n 0..63]. t1 prefetched one stage ahead.
// Waves 4-7 CONSUME: wave c owns m rows [mb+c*32,+32) x all 192 cols; per
//   stage: 24 y b128 loads (issued BEFORE the flag spin -> L2 latency
//   absorbed), 4 B-frag b128 LDS reads (shared across 6 coltiles), 24 MFMAs.
// Ring sync: monotonic counters ready[s]/freed[s] (4 per occurrence),
// lane-0 atomicAdd, volatile spin + s_sleep, threadfence_block ordering.
__global__ __launch_bounds__(512) void k_mega(const unsigned short* __restrict__ t1b,
                                              const unsigned short* __restrict__ nv2b,
                                              const unsigned short* __restrict__ yT,
                                              float* __restrict__ part) {
  __shared__ unsigned short Et[RSLOT][128][64];  // 49152 B
  __shared__ int flg[2 * RSLOT];                 // [0..R) ready, [R..2R) freed
  const int tid = threadIdx.x;
  const int w = tid >> 6, lane = tid & 63;
  const int h = lane >> 5, l31 = lane & 31;
  const int mb = blockIdx.x * 128;
  const int nt0 = blockIdx.y * CHUNK;
  const int swz = (l31 & 7) << 3;
  if (tid < 2 * RSLOT) flg[tid] = 0;
  __syncthreads();
  volatile int* vflg = flg;

  if (w < 4) {
    // ======================= PRODUCER =======================
    const int p = w;
    bf16x8 bn0 = *(const bf16x8*)(nv2b + (size_t)(mb + p * 32 + l31) * DD + h * 8);
    bf16x8 bn1 = *(const bf16x8*)(nv2b + (size_t)(mb + p * 32 + l31) * DD + 16 + h * 8);
    f32x16 z16;
#pragma unroll
    for (int r = 0; r < 16; ++r) z16[r] = 0.f;

    // t1 frags for stage 0 (2 n-subtiles x 2 k-halves)
    bf16x8 at[4], nx[4];
#pragma unroll
    for (int ns = 0; ns < 2; ++ns) {
      const size_t rowb = (size_t)(nt0 + ns * 32 + l31) * DD;
      at[ns * 2 + 0] = *(const bf16x8*)(t1b + rowb + h * 8);
      at[ns * 2 + 1] = *(const bf16x8*)(t1b + rowb + 16 + h * 8);
    }
    for (int st = 0; st < 16; ++st) {
      const int s = st % RSLOT;
      const int occ = st / RSLOT;
      // prefetch next stage's t1 (in flight across the wait + compute)
      if (st < 15) {
#pragma unroll
        for (int ns = 0; ns < 2; ++ns) {
          const size_t rowb = (size_t)(nt0 + (st + 1) * 64 + ns * 32 + l31) * DD;
          nx[ns * 2 + 0] = *(const bf16x8*)(t1b + rowb + h * 8);
          nx[ns * 2 + 1] = *(const bf16x8*)(t1b + rowb + 16 + h * 8);
        }
      }
      if (occ > 0) {
        const int tgt = 4 * occ;  // previous occupant fully consumed
        while (vflg[RSLOT + s] < tgt) __builtin_amdgcn_s_sleep(1);
      }
      __threadfence_block();
#pragma unroll
      for (int ns = 0; ns < 2; ++ns) {
        f32x16 d = __builtin_amdgcn_mfma_f32_32x32x16_bf16(at[ns * 2 + 1], bn1, z16, 0, 0, 0);
        d = __builtin_amdgcn_mfma_f32_32x32x16_bf16(at[ns * 2 + 0], bn0, d, 0, 0, 0);
        // C-layout: lane l31 = m-local(+p*32); reg r -> n-local = ns*32 + 8*(r>>2) + 4*h + (r&3)
#pragma unroll
        for (int g = 0; g < 4; ++g) {
          bf16x4 ev;
#pragma unroll
          for (int b = 0; b < 4; ++b)
            ev[b] = (short)f2bf(fexp2(fmaxf(d[4 * g + b], 0.f)));
          *(bf16x4*)&Et[s][p * 32 + l31][(ns * 32 + 8 * g + 4 * h) ^ swz] = ev;
        }
      }
      __threadfence_block();
      if (lane == 0) atomicAdd(&flg[s], 1);
#pragma unroll
      for (int r = 0; r < 4; ++r) at[r] = nx[r];
    }
  } else {
    // ======================= CONSUMER =======================
    const int c = w - 4;
    f32x16 acc[6];
#pragma unroll
    for (int ct = 0; ct < 6; ++ct)
#pragma unroll
      for (int r = 0; r < 16; ++r) acc[ct][r] = 0.f;

    for (int st = 0; st < 16; ++st) {
      const int s = st % RSLOT;
      const int tgt = 4 * (st / RSLOT + 1);
      const int nb = nt0 + st * 64;
      // y A-frags issued before the spin — L2 latency absorbed by the wait
      bf16x8 yf[6][4];
#pragma unroll
      for (int ct = 0; ct < 6; ++ct) {
        const unsigned short* yp = yT + (size_t)(ct * 32 + l31) * NN + nb + h * 8;
#pragma unroll
        for (int ks = 0; ks < 4; ++ks) yf[ct][ks] = *(const bf16x8*)(yp + ks * 16);
      }
      while (vflg[s] < tgt) __builtin_amdgcn_s_sleep(1);
      __threadfence_block();
      // B-frags: B[k=h*8+j][m=l31] = Et[s][c*32+l31][ks*16 + h*8 + j]
      bf16x8 bf[4];
#pragma unroll
      for (int ks = 0; ks < 4; ++ks)
        bf[ks] = *(const bf16x8*)&Et[s][c * 32 + l31][(ks * 16 + h * 8) ^ swz];
#pragma unroll
      for (int ct = 0; ct < 6; ++ct)
#pragma unroll
        for (int ks = 0; ks < 4; ++ks)
          acc[ct] = __builtin_amdgcn_mfma_f32_32x32x16_bf16(yf[ct][ks], bf[ks], acc[ct], 0, 0, 0);
      __threadfence_block();
      if (lane == 0) atomicAdd(&flg[RSLOT + s], 1);
    }
    // epilogue: acc[ct] reg r -> col = ct*32 + (r&3) + 8*(r>>2) + 4*h, m = mb + c*32 + l31
    float* pp = part + (size_t)blockIdx.y * 192 * NN;
#pragma unroll
    for (int ct = 0; ct < 6; ++ct)
#pragma unroll
      for (int r = 0; r < 16; ++r) {
        const int col = ct * 32 + (r & 3) + 8 * (r >> 2) + 4 * h;
        pp[(size_t)col * NN + mb + c * 32 + l31] = acc[ct][r];
      }
  }
}

// ---- reduce NSPLIT partials + transpose to out[bc][m][t] ----
__global__ __launch_bounds__(256) void k_reduce(const float* __restrict__ part,
                                                float* __restrict__ out) {
  __shared__ float os[3072];
  const int tid = threadIdx.x;
  const int m0 = blockIdx.x * 256;
  const int bc = blockIdx.y;
#pragma unroll
  for (int t = 0; t < 12; ++t) {
    const int col = bc * TT + t;
    float s = 0.f;
#pragma unroll
    for (int nc = 0; nc < NSPLIT; ++nc)
      s += part[((size_t)nc * 192 + col) * NN + m0 + tid];
    os[tid * 12 + t] = s;
  }
  __syncthreads();
  float* op = out + (size_t)bc * NN * TT + (size_t)m0 * TT;
#pragma unroll
  for (int j = 0; j < 12; ++j) op[j * 256 + tid] = os[j * 256 + tid];
}

extern "C" void kernel_launch(void* const* d_in, const int* in_sizes, int n_in,
                              void* d_out, int out_size, void* d_ws, size_t ws_size,
                              hipStream_t stream) {
  const float* x = (const float*)d_in[0];
  const float* nv1 = (const float*)d_in[1];
  const float* nv2 = (const float*)d_in[2];
  const float* tv = (const float*)d_in[3];
  const float* kk = (const float*)d_in[4];
  const int* tind = (const int*)d_in[5];
  float* out = (float*)d_out;

  char* ws = (char*)d_ws;
  unsigned short* t1b  = (unsigned short*)(ws);            //  524288 B
  unsigned short* nv2b = (unsigned short*)(ws + 524288);   //  524288 B
  float* sums          = (float*)(ws + 1048576);           //   32768 B
  unsigned short* yT   = (unsigned short*)(ws + 1081344);  // 3145728 B -> 4227072
  float* part          = (float*)(ws + 4227072);           // 50331648 B -> 54558720

  k_prep<<<64, 256, 0, stream>>>(nv1, nv2, tv, kk, tind, t1b, nv2b, sums);
  k_stats<<<dim3(128, 8), 256, 0, stream>>>(t1b, nv2b, sums);
  k_y<<<dim3(32, 16), 256, 0, stream>>>(x, sums, yT);
  k_mega<<<dim3(64, NSPLIT), 512, 0, stream>>>(t1b, nv2b, yT, part);
  k_reduce<<<dim3(32, 16), 256, 0, stream>>>(part, out);
}

// Round 11
// 178.843 us; speedup vs baseline: 1.2221x; 1.2221x over previous
//
#include <hip/hip_runtime.h>
#include <hip/hip_bf16.h>

// GDGCN: out[b,c,m,t] = sum_n softmax_row(relu(t1 nv2^T))[n,m] * x[b,c,n,t]
// t1 = nv1 @ (sum_d tv[d] k[d,:,:]);  N=8192, D=32, cols = B*C*T = 192.
// R11: k_mega = R6's proven barrier-dbuf structure, reconfigured for FOUR
// independent barrier domains per CU: 256-thr/4-wave blocks, 64-m tile,
// grid 128x8 = 1024 blocks = 4 blocks/CU (16 waves/CU). Block A's barrier
// drain overlaps block B's MFMA issue (m114 co-scheduling). Per-block y
// duplication drops 2x -> 1x, so L2 traffic unchanged. All other kernels
// verbatim from R8.

#define NN 8192
#define DD 32
#define TT 12
#define NSPLIT 8
#define CHUNK 1024
#define ESTR 72  // LDS row stride (ushort); R6-proven layout

typedef __attribute__((ext_vector_type(8))) short bf16x8;
typedef __attribute__((ext_vector_type(4))) short bf16x4;
typedef __attribute__((ext_vector_type(4))) float f32x4;

static __device__ __forceinline__ unsigned short f2bf(float f) {
  unsigned int u = __float_as_uint(f);
  u = (u + 0x7FFFu + ((u >> 16) & 1u)) >> 16;  // RNE bf16
  return (unsigned short)u;
}

static __device__ __forceinline__ float fexp2(float x) {
#if __has_builtin(__builtin_amdgcn_exp2f)
  return __builtin_amdgcn_exp2f(x);
#else
  return __builtin_exp2f(x);
#endif
}

// ---- fused: core = tv.k ; t1 = (nv1@core)*log2e (bf16) ; nv2 -> bf16 ; sums=0
__global__ __launch_bounds__(256) void k_prep(const float* __restrict__ nv1,
                                              const float* __restrict__ nv2,
                                              const float* __restrict__ timevec,
                                              const float* __restrict__ kk,
                                              const int* __restrict__ tind,
                                              unsigned short* __restrict__ t1b,
                                              unsigned short* __restrict__ nv2b,
                                              float* __restrict__ sums) {
  __shared__ float cs[1024];
  const int tid = threadIdx.x;
  if (tid < 128) sums[blockIdx.x * 128 + tid] = 0.f;
  const float* tv = timevec + (size_t)tind[0] * DD;
  for (int idx = tid; idx < 1024; idx += 256) {
    float acc = 0.f;
#pragma unroll
    for (int d = 0; d < DD; ++d) acc += tv[d] * kk[d * 1024 + idx];
    cs[idx] = acc;
  }
  __syncthreads();
  const int nbase = blockIdx.x * 128;
  const int f = tid & 31, sub = tid >> 5;
#pragma unroll 4
  for (int it = 0; it < 16; ++it) {
    const int n = nbase + it * 8 + sub;
    const float* nr = nv1 + (size_t)n * DD;
    float acc = 0.f;
#pragma unroll
    for (int e = 0; e < DD; ++e) acc += nr[e] * cs[e * DD + f];
    t1b[(size_t)n * DD + f] = f2bf(acc * 1.4426950408889634f);  // fold log2(e)
  }
#pragma unroll 4
  for (int it = 0; it < 16; ++it) {
    const int idx = nbase * DD + it * 256 + tid;
    nv2b[idx] = f2bf(nv2[idx]);
  }
}

// ---- sums[n] += sum_m exp2(relu(t1[n].nv2[m]))  grid (128 n, 8 m-chunks) ----
__global__ __launch_bounds__(256) void k_stats(const unsigned short* __restrict__ t1b,
                                               const unsigned short* __restrict__ nv2b,
                                               float* __restrict__ sums) {
  const int tid = threadIdx.x;
  const int w = tid >> 6, lane = tid & 63, q = lane >> 4, i16 = lane & 15;
  const int nbase = blockIdx.x * 64 + w * 16;
  bf16x8 a = *(const bf16x8*)(t1b + (size_t)(nbase + i16) * DD + q * 8);
  const f32x4 z4 = {0.f, 0.f, 0.f, 0.f};
  float s[4] = {0.f, 0.f, 0.f, 0.f};
  const int m0 = blockIdx.y * 1024;
  for (int mt = m0; mt < m0 + 1024; mt += 64) {
#pragma unroll
    for (int u = 0; u < 4; ++u) {
      bf16x8 b = *(const bf16x8*)(nv2b + (size_t)(mt + u * 16 + i16) * DD + q * 8);
      f32x4 d = __builtin_amdgcn_mfma_f32_16x16x32_bf16(a, b, z4, 0, 0, 0);
#pragma unroll
      for (int r = 0; r < 4; ++r) s[r] += fexp2(fmaxf(d[r], 0.f));
    }
  }
#pragma unroll
  for (int r = 0; r < 4; ++r)
    for (int off = 1; off < 16; off <<= 1) s[r] += __shfl_xor(s[r], off, 64);
  if (i16 == 0) {
#pragma unroll
    for (int r = 0; r < 4; ++r) atomicAdd(&sums[nbase + q * 4 + r], s[r]);
  }
}

// ---- yT[col][n] = bf16(x[bc][n][t] / sums[n]) via LDS transpose ----
__global__ __launch_bounds__(256) void k_y(const float* __restrict__ x,
                                           const float* __restrict__ sums,
                                           unsigned short* __restrict__ yT) {
  __shared__ float xs[3072];
  const int tid = threadIdx.x;
  const int n0 = blockIdx.x * 256;
  const int bc = blockIdx.y;
  const float* xp = x + (size_t)bc * NN * TT + (size_t)n0 * TT;
#pragma unroll
  for (int j = 0; j < 12; ++j) xs[j * 256 + tid] = xp[j * 256 + tid];
  __syncthreads();
  const float rinv = 1.0f / sums[n0 + tid];
#pragma unroll
  for (int t = 0; t < 12; ++t)
    yT[(size_t)(bc * TT + t) * NN + n0 + tid] = f2bf(xs[tid * 12 + t] * rinv);
}

// ---- k_mega: part[nc][col][m] = sum_{n in chunk} E[n][m] * y[col][n] ----
// grid (128 m-blocks of 64, 8 chunks of 1024 n); 256 thr = 4 waves.
// Stage = 64 n, double-buffered Et[2][64][ESTR]. Gen: wave w -> E rows
// [w*16,w*16+16) x 64 n (4 MFMAs + 16 exp2 + 4 b64 writes). Acc: wave w ->
// coltiles [w*3,w*3+3) x 4 m-subs x 2 k-steps = 24 MFMAs. One barrier/stage.
// 4 blocks/CU = 4 independent barrier domains.
__global__ __launch_bounds__(256, 4) void k_mega(const unsigned short* __restrict__ t1b,
                                                 const unsigned short* __restrict__ nv2b,
                                                 const unsigned short* __restrict__ yT,
                                                 float* __restrict__ part) {
  const int tid = threadIdx.x;
  const int w = tid >> 6, lane = tid & 63, q = lane >> 4, i16 = lane & 15;
  const int mb = blockIdx.x * 64;
  const int nt0 = blockIdx.y * CHUNK;

  __shared__ unsigned short Ew[2][64][ESTR];  // 18432 B

  // gen B-frag (loop-invariant): B[d][m=i16] = nv2[mb + w*16 + i16][d]
  const bf16x8 bg = *(const bf16x8*)(nv2b + (size_t)(mb + w * 16 + i16) * DD + q * 8);
  const int rowm = w * 16 + i16;

  const f32x4 z4 = {0.f, 0.f, 0.f, 0.f};
  f32x4 acc[3][4];
#pragma unroll
  for (int c = 0; c < 3; ++c)
#pragma unroll
    for (int ms = 0; ms < 4; ++ms) acc[c][ms] = (f32x4){0.f, 0.f, 0.f, 0.f};

  // ---- prologue: generate stage 0 (64 n) into buf 0 ----
#pragma unroll
  for (int s = 0; s < 4; ++s) {
    bf16x8 at = *(const bf16x8*)(t1b + (size_t)(nt0 + s * 16 + i16) * DD + q * 8);
    f32x4 d = __builtin_amdgcn_mfma_f32_16x16x32_bf16(at, bg, z4, 0, 0, 0);
    bf16x4 e;
#pragma unroll
    for (int r = 0; r < 4; ++r) e[r] = (short)f2bf(fexp2(fmaxf(d[r], 0.f)));
    *(bf16x4*)&Ew[0][rowm][s * 16 + q * 4] = e;
  }
  __syncthreads();

  int p = 0;
  for (int st = 0; st < 16; ++st, p ^= 1) {
    const int nt = nt0 + st * 64;
    const bool more = (st < 15);

    // next-stage t1 A-frags, issued at stage top for latency
    bf16x8 atn[4];
    if (more) {
#pragma unroll
      for (int s = 0; s < 4; ++s)
        atn[s] = *(const bf16x8*)(t1b + (size_t)(nt + 64 + s * 16 + i16) * DD + q * 8);
    }

    // half-0 operands (k-step 0: n 0..31 of stage)
    bf16x8 yfr[3], efr[4];
#pragma unroll
    for (int c = 0; c < 3; ++c)
      yfr[c] = *(const bf16x8*)(yT + (size_t)((w * 3 + c) * 16 + i16) * NN + nt + q * 8);
#pragma unroll
    for (int ms = 0; ms < 4; ++ms)
      efr[ms] = *(const bf16x8*)&Ew[p][ms * 16 + i16][q * 8];

    // gen first half (s0,s1) for stage st+1
    f32x4 d0, d1;
    if (more) {
      d0 = __builtin_amdgcn_mfma_f32_16x16x32_bf16(atn[0], bg, z4, 0, 0, 0);
      d1 = __builtin_amdgcn_mfma_f32_16x16x32_bf16(atn[1], bg, z4, 0, 0, 0);
    }

    // acc k-step 0 (12 MFMAs)
#pragma unroll
    for (int c = 0; c < 3; ++c)
#pragma unroll
      for (int ms = 0; ms < 4; ++ms)
        acc[c][ms] = __builtin_amdgcn_mfma_f32_16x16x32_bf16(yfr[c], efr[ms], acc[c][ms], 0, 0, 0);

    // exp2 + store s0,s1; gen + store s2,s3 (VALU overlaps MFMA pipes)
    if (more) {
      bf16x4 e0, e1;
#pragma unroll
      for (int r = 0; r < 4; ++r) {
        e0[r] = (short)f2bf(fexp2(fmaxf(d0[r], 0.f)));
        e1[r] = (short)f2bf(fexp2(fmaxf(d1[r], 0.f)));
      }
      *(bf16x4*)&Ew[p ^ 1][rowm][q * 4] = e0;
      *(bf16x4*)&Ew[p ^ 1][rowm][16 + q * 4] = e1;
      f32x4 d2 = __builtin_amdgcn_mfma_f32_16x16x32_bf16(atn[2], bg, z4, 0, 0, 0);
      f32x4 d3 = __builtin_amdgcn_mfma_f32_16x16x32_bf16(atn[3], bg, z4, 0, 0, 0);
      bf16x4 e2, e3;
#pragma unroll
      for (int r = 0; r < 4; ++r) {
        e2[r] = (short)f2bf(fexp2(fmaxf(d2[r], 0.f)));
        e3[r] = (short)f2bf(fexp2(fmaxf(d3[r], 0.f)));
      }
      *(bf16x4*)&Ew[p ^ 1][rowm][32 + q * 4] = e2;
      *(bf16x4*)&Ew[p ^ 1][rowm][48 + q * 4] = e3;
    }

    // half-1 operands + acc (k-step 1: n 32..63)
#pragma unroll
    for (int c = 0; c < 3; ++c)
      yfr[c] = *(const bf16x8*)(yT + (size_t)((w * 3 + c) * 16 + i16) * NN + nt + 32 + q * 8);
#pragma unroll
    for (int ms = 0; ms < 4; ++ms)
      efr[ms] = *(const bf16x8*)&Ew[p][ms * 16 + i16][32 + q * 8];
#pragma unroll
    for (int c = 0; c < 3; ++c)
#pragma unroll
      for (int ms = 0; ms < 4; ++ms)
        acc[c][ms] = __builtin_amdgcn_mfma_f32_16x16x32_bf16(yfr[c], efr[ms], acc[c][ms], 0, 0, 0);

    __syncthreads();  // buf p reads done; buf p^1 writes visible
  }

  // epilogue: lane holds col = (w*3+c)*16 + q*4 + r, m = mb + ms*16 + i16
  float* pp = part + (size_t)blockIdx.y * 192 * NN;
#pragma unroll
  for (int c = 0; c < 3; ++c)
#pragma unroll
    for (int ms = 0; ms < 4; ++ms) {
      const int colbase = (w * 3 + c) * 16 + q * 4;
      const int m = mb + ms * 16 + i16;
#pragma unroll
      for (int r = 0; r < 4; ++r)
        pp[(size_t)(colbase + r) * NN + m] = acc[c][ms][r];
    }
}

// ---- reduce NSPLIT partials + transpose to out[bc][m][t] ----
__global__ __launch_bounds__(256) void k_reduce(const float* __restrict__ part,
                                                float* __restrict__ out) {
  __shared__ float os[3072];
  const int tid = threadIdx.x;
  const int m0 = blockIdx.x * 256;
  const int bc = blockIdx.y;
#pragma unroll
  for (int t = 0; t < 12; ++t) {
    const int col = bc * TT + t;
    float s = 0.f;
#pragma unroll
    for (int nc = 0; nc < NSPLIT; ++nc)
      s += part[((size_t)nc * 192 + col) * NN + m0 + tid];
    os[tid * 12 + t] = s;
  }
  __syncthreads();
  float* op = out + (size_t)bc * NN * TT + (size_t)m0 * TT;
#pragma unroll
  for (int j = 0; j < 12; ++j) op[j * 256 + tid] = os[j * 256 + tid];
}

extern "C" void kernel_launch(void* const* d_in, const int* in_sizes, int n_in,
                              void* d_out, int out_size, void* d_ws, size_t ws_size,
                              hipStream_t stream) {
  const float* x = (const float*)d_in[0];
  const float* nv1 = (const float*)d_in[1];
  const float* nv2 = (const float*)d_in[2];
  const float* tv = (const float*)d_in[3];
  const float* kk = (const float*)d_in[4];
  const int* tind = (const int*)d_in[5];
  float* out = (float*)d_out;

  char* ws = (char*)d_ws;
  unsigned short* t1b  = (unsigned short*)(ws);            //  524288 B
  unsigned short* nv2b = (unsigned short*)(ws + 524288);   //  524288 B
  float* sums          = (float*)(ws + 1048576);           //   32768 B
  unsigned short* yT   = (unsigned short*)(ws + 1081344);  // 3145728 B -> 4227072
  float* part          = (float*)(ws + 4227072);           // 50331648 B -> 54558720

  k_prep<<<64, 256, 0, stream>>>(nv1, nv2, tv, kk, tind, t1b, nv2b, sums);
  k_stats<<<dim3(128, 8), 256, 0, stream>>>(t1b, nv2b, sums);
  k_y<<<dim3(32, 16), 256, 0, stream>>>(x, sums, yT);
  k_mega<<<dim3(128, NSPLIT), 256, 0, stream>>>(t1b, nv2b, yT, part);
  k_reduce<<<dim3(32, 16), 256, 0, stream>>>(part, out);
}